// Round 1
// baseline (6576.579 us; speedup 1.0000x reference)
//
#include <hip/hip_runtime.h>

#define N_NODES 100000
#define N_EDGES 500000
#define NODE_IN 60
#define EDGE_IN 8
#define HID 256
#define NLAYERS 8
#define NGRAPH 64
#define BN_EPS 1e-5f
#define EPB 32

// ---------------- GEMM: C[M,256] = relu([BN](A[M,K] @ B[K,256] + bias)) ------
// BM=64, BN=64, BK=16, 256 threads, 4x4 micro-tile per thread.
template<bool WITH_BN>
__global__ __launch_bounds__(256)
void gemm_kernel(const float* __restrict__ A, int lda, int K,
                 const float* __restrict__ B,          // [K,256] row-major
                 const float* __restrict__ bias,
                 const float* __restrict__ gamma, const float* __restrict__ beta,
                 const float* __restrict__ mean,  const float* __restrict__ var,
                 float* __restrict__ C, int M)
{
    __shared__ float As[16][68];   // [k][row] (transposed), padded
    __shared__ float Bs[16][68];   // [k][col], padded

    const int tid = threadIdx.x;
    const int tx = tid & 15, ty = tid >> 4;
    const int m0 = blockIdx.x * 64;
    const int n0 = blockIdx.y * 64;

    const int ar = tid >> 2;         // 0..63  A row within tile
    const int ac = (tid & 3) * 4;    // 0,4,8,12  k offset
    const int br = tid >> 4;         // 0..15  B k-row
    const int bc = (tid & 15) * 4;   // 0..60  B col offset

    float acc[4][4] = {};

    for (int k0 = 0; k0 < K; k0 += 16) {
        // stage A tile (transposed into As[k][row])
        float4 av = make_float4(0.f, 0.f, 0.f, 0.f);
        const int arow = m0 + ar;
        if (arow < M) {
            if (k0 + ac + 3 < K) {
                av = *(const float4*)&A[(size_t)arow * lda + k0 + ac];
            } else {
                float t0 = (k0 + ac + 0 < K) ? A[(size_t)arow * lda + k0 + ac + 0] : 0.f;
                float t1 = (k0 + ac + 1 < K) ? A[(size_t)arow * lda + k0 + ac + 1] : 0.f;
                float t2 = (k0 + ac + 2 < K) ? A[(size_t)arow * lda + k0 + ac + 2] : 0.f;
                float t3 = (k0 + ac + 3 < K) ? A[(size_t)arow * lda + k0 + ac + 3] : 0.f;
                av = make_float4(t0, t1, t2, t3);
            }
        }
        As[ac + 0][ar] = av.x;
        As[ac + 1][ar] = av.y;
        As[ac + 2][ar] = av.z;
        As[ac + 3][ar] = av.w;

        // stage B tile
        float4 bv = make_float4(0.f, 0.f, 0.f, 0.f);
        if (k0 + br < K) bv = *(const float4*)&B[(size_t)(k0 + br) * HID + n0 + bc];
        *(float4*)&Bs[br][bc] = bv;

        __syncthreads();
        #pragma unroll
        for (int k = 0; k < 16; ++k) {
            float4 a4 = *(const float4*)&As[k][ty * 4];
            float4 b4 = *(const float4*)&Bs[k][tx * 4];
            acc[0][0] += a4.x * b4.x; acc[0][1] += a4.x * b4.y; acc[0][2] += a4.x * b4.z; acc[0][3] += a4.x * b4.w;
            acc[1][0] += a4.y * b4.x; acc[1][1] += a4.y * b4.y; acc[1][2] += a4.y * b4.z; acc[1][3] += a4.y * b4.w;
            acc[2][0] += a4.z * b4.x; acc[2][1] += a4.z * b4.y; acc[2][2] += a4.z * b4.z; acc[2][3] += a4.z * b4.w;
            acc[3][0] += a4.w * b4.x; acc[3][1] += a4.w * b4.y; acc[3][2] += a4.w * b4.z; acc[3][3] += a4.w * b4.w;
        }
        __syncthreads();
    }

    #pragma unroll
    for (int i = 0; i < 4; ++i) {
        const int row = m0 + ty * 4 + i;
        if (row >= M) continue;
        #pragma unroll
        for (int j = 0; j < 4; ++j) {
            const int col = n0 + tx * 4 + j;
            float v = acc[i][j] + bias[col];
            if (WITH_BN)
                v = (v - mean[col]) * (gamma[col] * rsqrtf(var[col] + BN_EPS)) + beta[col];
            v = fmaxf(v, 0.f);
            C[(size_t)row * HID + col] = v;
        }
    }
}

// ------------- edge message + scatter-add aggregation ------------------------
// agg[dst] += relu(h[src] + edge_attr @ W + b), 32 edges per 256-thread block
__global__ __launch_bounds__(256)
void msg_agg_kernel(const float* __restrict__ h, const float* __restrict__ ea,
                    const int* __restrict__ src, const int* __restrict__ dst,
                    const float* __restrict__ W,   // [8,256]
                    const float* __restrict__ b,   // [256]
                    float* __restrict__ agg, int E)
{
    __shared__ float Ws[EDGE_IN][HID];
    __shared__ float bs[HID];
    __shared__ float eas[EPB][EDGE_IN];

    const int t = threadIdx.x;
    #pragma unroll
    for (int k = 0; k < EDGE_IN; ++k) Ws[k][t] = W[k * HID + t];
    bs[t] = b[t];

    const int e0 = blockIdx.x * EPB;
    const int ne = min(EPB, E - e0);
    if (t < ne * EDGE_IN) eas[t / EDGE_IN][t % EDGE_IN] = ea[(size_t)(e0 + t / EDGE_IN) * EDGE_IN + t % EDGE_IN];
    __syncthreads();

    for (int i = 0; i < ne; ++i) {
        const int s = src[e0 + i];
        const int d = dst[e0 + i];
        float ev = bs[t];
        #pragma unroll
        for (int k = 0; k < EDGE_IN; ++k) ev += eas[i][k] * Ws[k][t];
        float m = h[(size_t)s * HID + t] + ev;
        m = fmaxf(m, 0.f);
        atomicAdd(&agg[(size_t)d * HID + t], m);
    }
}

// ------------- z = (1+eps)*h + agg  (in place on agg) ------------------------
__global__ __launch_bounds__(256)
void zpass_kernel(const float* __restrict__ h, float* __restrict__ agg,
                  const float* __restrict__ eps, int l, size_t n4)
{
    const float e1 = 1.0f + eps[l];
    size_t i = (size_t)blockIdx.x * blockDim.x + threadIdx.x;
    const size_t stride = (size_t)gridDim.x * blockDim.x;
    for (; i < n4; i += stride) {
        float4 hv = ((const float4*)h)[i];
        float4 av = ((float4*)agg)[i];
        av.x += e1 * hv.x; av.y += e1 * hv.y; av.z += e1 * hv.z; av.w += e1 * hv.w;
        ((float4*)agg)[i] = av;
    }
}

// ------------- global mean pool (batch ids sorted): run-length + atomics -----
__global__ __launch_bounds__(256)
void pool_kernel(const float* __restrict__ h, const int* __restrict__ batch,
                 float* __restrict__ gsum, int* __restrict__ cnt, int n)
{
    __shared__ int bsh[256];
    const int t = threadIdx.x;
    const int n0 = blockIdx.x * 256;
    const int nn = min(256, n - n0);
    if (t < nn) bsh[t] = batch[n0 + t];
    __syncthreads();

    int gcur = bsh[0];
    float acc = 0.f;
    int c = 0;
    for (int i = 0; i < nn; ++i) {
        const int g = bsh[i];
        if (g != gcur) {
            atomicAdd(&gsum[gcur * HID + t], acc);
            if (t == 0) atomicAdd(&cnt[gcur], c);
            acc = 0.f; c = 0; gcur = g;
        }
        acc += h[(size_t)(n0 + i) * HID + t];
        c++;
    }
    atomicAdd(&gsum[gcur * HID + t], acc);
    if (t == 0) atomicAdd(&cnt[gcur], c);
}

// ------------- head: g = gsum/cnt; out = relu(g@W1+b1)@W2 + b2 --------------
__global__ __launch_bounds__(128)
void head_kernel(const float* __restrict__ gsum, const int* __restrict__ cnt,
                 const float* __restrict__ W1, const float* __restrict__ b1,
                 const float* __restrict__ W2, const float* __restrict__ b2,
                 float* __restrict__ out)
{
    const int gi = blockIdx.x;
    const int j = threadIdx.x; // 0..127
    __shared__ float gs[HID];
    __shared__ float red[128];

    const float c = fmaxf((float)cnt[gi], 1.0f);
    gs[j]       = gsum[gi * HID + j] / c;
    gs[j + 128] = gsum[gi * HID + 128 + j] / c;
    __syncthreads();

    float acc = b1[j];
    #pragma unroll 8
    for (int k = 0; k < HID; ++k) acc += gs[k] * W1[k * 128 + j];
    acc = fmaxf(acc, 0.f);
    red[j] = acc * W2[j];
    __syncthreads();
    for (int s = 64; s > 0; s >>= 1) {
        if (j < s) red[j] += red[j + s];
        __syncthreads();
    }
    if (j == 0) out[gi] = red[0] + b2[0];
}

extern "C" void kernel_launch(void* const* d_in, const int* in_sizes, int n_in,
                              void* d_out, int out_size, void* d_ws, size_t ws_size,
                              hipStream_t stream)
{
    const float* x         = (const float*)d_in[0];
    const int*   ei        = (const int*)d_in[1];
    const float* edge_attr = (const float*)d_in[2];
    const int*   batch     = (const int*)d_in[3];
    const float* xproj_W   = (const float*)d_in[4];
    const float* xproj_b   = (const float*)d_in[5];
    const float* xp_gamma  = (const float*)d_in[6];
    const float* xp_beta   = (const float*)d_in[7];
    const float* xp_mean   = (const float*)d_in[8];
    const float* xp_var    = (const float*)d_in[9];
    const float* edge_W    = (const float*)d_in[10];
    const float* edge_b    = (const float*)d_in[11];
    const float* mlp_W1    = (const float*)d_in[12];
    const float* mlp_b1    = (const float*)d_in[13];
    const float* mlp_W2    = (const float*)d_in[14];
    const float* mlp_b2    = (const float*)d_in[15];
    const float* eps       = (const float*)d_in[16];
    const float* bn_gamma  = (const float*)d_in[17];
    const float* bn_beta   = (const float*)d_in[18];
    const float* bn_mean   = (const float*)d_in[19];
    const float* bn_var    = (const float*)d_in[20];
    const float* head_W1   = (const float*)d_in[21];
    const float* head_b1   = (const float*)d_in[22];
    const float* head_W2   = (const float*)d_in[23];
    const float* head_b2   = (const float*)d_in[24];
    float* out = (float*)d_out;

    const int* srcI = ei;
    const int* dstI = ei + N_EDGES;

    float* bufA = (float*)d_ws;
    float* bufB = bufA + (size_t)N_NODES * HID;
    float* gsum = bufB + (size_t)N_NODES * HID;
    int*   cnt  = (int*)(gsum + NGRAPH * HID);

    dim3 gemm_grid((N_NODES + 63) / 64, HID / 64);

    // x_proj: Linear + BN + ReLU -> bufA
    gemm_kernel<true><<<gemm_grid, 256, 0, stream>>>(
        x, NODE_IN, NODE_IN, xproj_W, xproj_b,
        xp_gamma, xp_beta, xp_mean, xp_var, bufA, N_NODES);

    for (int l = 0; l < NLAYERS; ++l) {
        hipMemsetAsync(bufB, 0, (size_t)N_NODES * HID * sizeof(float), stream);
        msg_agg_kernel<<<(N_EDGES + EPB - 1) / EPB, 256, 0, stream>>>(
            bufA, edge_attr, srcI, dstI,
            edge_W + (size_t)l * EDGE_IN * HID, edge_b + (size_t)l * HID, bufB, N_EDGES);
        zpass_kernel<<<2048, 256, 0, stream>>>(bufA, bufB, eps, l, (size_t)N_NODES * HID / 4);
        gemm_kernel<false><<<gemm_grid, 256, 0, stream>>>(
            bufB, HID, HID, mlp_W1 + (size_t)l * HID * HID, mlp_b1 + (size_t)l * HID,
            nullptr, nullptr, nullptr, nullptr, bufA, N_NODES);
        gemm_kernel<true><<<gemm_grid, 256, 0, stream>>>(
            bufA, HID, HID, mlp_W2 + (size_t)l * HID * HID, mlp_b2 + (size_t)l * HID,
            bn_gamma + (size_t)l * HID, bn_beta + (size_t)l * HID,
            bn_mean + (size_t)l * HID, bn_var + (size_t)l * HID, bufB, N_NODES);
        float* tmp = bufA; bufA = bufB; bufB = tmp;
    }

    hipMemsetAsync(gsum, 0, (size_t)NGRAPH * HID * sizeof(float) + NGRAPH * sizeof(int), stream);
    pool_kernel<<<(N_NODES + 255) / 256, 256, 0, stream>>>(bufA, batch, gsum, cnt, N_NODES);
    head_kernel<<<NGRAPH, 128, 0, stream>>>(gsum, cnt, head_W1, head_b1, head_W2, head_b2, out);
}

// Round 2
// 2372.396 us; speedup vs baseline: 2.7721x; 2.7721x over previous
//
#include <hip/hip_runtime.h>

#define N_NODES 100000
#define N_EDGES 500000
#define NODE_IN 60
#define EDGE_IN 8
#define HID 256
#define NLAYERS 8
#define NGRAPH 64
#define BN_EPS 1e-5f

typedef __attribute__((ext_vector_type(4))) float f32x4;
typedef __attribute__((ext_vector_type(4))) short short4v;
typedef __attribute__((ext_vector_type(8))) short short8v;

__device__ __forceinline__ unsigned short f2bf(float f) {
    unsigned int u = __builtin_bit_cast(unsigned int, f);
    u += 0x7fffu + ((u >> 16) & 1u);
    return (unsigned short)(u >> 16);
}

// ---------------- f32 GEMM for x_proj only (K=60) ---------------------------
__global__ __launch_bounds__(256)
void gemm_f32_kernel(const float* __restrict__ A, int lda, int K,
                     const float* __restrict__ B,
                     const float* __restrict__ bias,
                     const float* __restrict__ gamma, const float* __restrict__ beta,
                     const float* __restrict__ mean,  const float* __restrict__ var,
                     float* __restrict__ C, int M)
{
    __shared__ float As[16][68];
    __shared__ float Bs[16][68];

    const int tid = threadIdx.x;
    const int tx = tid & 15, ty = tid >> 4;
    const int m0 = blockIdx.x * 64;
    const int n0 = blockIdx.y * 64;

    const int ar = tid >> 2;
    const int ac = (tid & 3) * 4;
    const int br = tid >> 4;
    const int bc = (tid & 15) * 4;

    float acc[4][4] = {};

    for (int k0 = 0; k0 < K; k0 += 16) {
        float4 av = make_float4(0.f, 0.f, 0.f, 0.f);
        const int arow = m0 + ar;
        if (arow < M) {
            if (k0 + ac + 3 < K) {
                av = *(const float4*)&A[(size_t)arow * lda + k0 + ac];
            } else {
                float t0 = (k0 + ac + 0 < K) ? A[(size_t)arow * lda + k0 + ac + 0] : 0.f;
                float t1 = (k0 + ac + 1 < K) ? A[(size_t)arow * lda + k0 + ac + 1] : 0.f;
                float t2 = (k0 + ac + 2 < K) ? A[(size_t)arow * lda + k0 + ac + 2] : 0.f;
                float t3 = (k0 + ac + 3 < K) ? A[(size_t)arow * lda + k0 + ac + 3] : 0.f;
                av = make_float4(t0, t1, t2, t3);
            }
        }
        As[ac + 0][ar] = av.x;
        As[ac + 1][ar] = av.y;
        As[ac + 2][ar] = av.z;
        As[ac + 3][ar] = av.w;

        float4 bv = make_float4(0.f, 0.f, 0.f, 0.f);
        if (k0 + br < K) bv = *(const float4*)&B[(size_t)(k0 + br) * HID + n0 + bc];
        *(float4*)&Bs[br][bc] = bv;

        __syncthreads();
        #pragma unroll
        for (int k = 0; k < 16; ++k) {
            float4 a4 = *(const float4*)&As[k][ty * 4];
            float4 b4 = *(const float4*)&Bs[k][tx * 4];
            acc[0][0] += a4.x * b4.x; acc[0][1] += a4.x * b4.y; acc[0][2] += a4.x * b4.z; acc[0][3] += a4.x * b4.w;
            acc[1][0] += a4.y * b4.x; acc[1][1] += a4.y * b4.y; acc[1][2] += a4.y * b4.z; acc[1][3] += a4.y * b4.w;
            acc[2][0] += a4.z * b4.x; acc[2][1] += a4.z * b4.y; acc[2][2] += a4.z * b4.z; acc[2][3] += a4.z * b4.w;
            acc[3][0] += a4.w * b4.x; acc[3][1] += a4.w * b4.y; acc[3][2] += a4.w * b4.z; acc[3][3] += a4.w * b4.w;
        }
        __syncthreads();
    }

    #pragma unroll
    for (int i = 0; i < 4; ++i) {
        const int row = m0 + ty * 4 + i;
        if (row >= M) continue;
        #pragma unroll
        for (int j = 0; j < 4; ++j) {
            const int col = n0 + tx * 4 + j;
            float v = acc[i][j] + bias[col];
            v = (v - mean[col]) * (gamma[col] * rsqrtf(var[col] + BN_EPS)) + beta[col];
            v = fmaxf(v, 0.f);
            C[(size_t)row * HID + col] = v;
        }
    }
}

// ---------------- bf16 MFMA GEMM: C[M,256] = epi(A[M,256] @ B) --------------
// A bf16 [M,256]; Bt bf16 [256 cols][256 k] (pre-transposed weights).
// BM=128, BN=256(full), BK=64; 4 waves, wave w covers cols w*64..w*64+63.
template<bool WITH_BN, bool OUT_F32>
__global__ __launch_bounds__(256, 2)
void mfma_gemm(const unsigned short* A, const unsigned short* Bt,
               const float* __restrict__ bias,
               const float* __restrict__ gamma, const float* __restrict__ beta,
               const float* __restrict__ mean,  const float* __restrict__ var,
               void* Cout, int M)
{
    __shared__ unsigned short smem[(16384 + 32768) / 2];
    unsigned short* sA = smem;            // [128 rows][64 bf16] stride 128B, XOR-swizzled
    unsigned short* sB = smem + 8192;     // [256 cols][64 bf16] stride 128B, XOR-swizzled

    const int tid  = threadIdx.x;
    const int lane = tid & 63;
    const int wv   = tid >> 6;      // wave 0..3
    const int lrow = lane & 15;
    const int g    = lane >> 4;     // 0..3
    const int m0   = blockIdx.x * 128;

    f32x4 acc[8][4] = {};

    for (int k0 = 0; k0 < 256; k0 += 64) {
        // stage A: 128 rows x 128 bytes (16 KB)
        #pragma unroll
        for (int i = 0; i < 4; ++i) {
            const int p   = (i * 256 + tid) * 16;
            const int row = p >> 7;
            const int off = p & 127;
            uint4 v = make_uint4(0u, 0u, 0u, 0u);
            if (m0 + row < M)
                v = *(const uint4*)((const char*)A + ((size_t)(m0 + row) * 512 + k0 * 2 + off));
            *(uint4*)((char*)sA + row * 128 + (off ^ ((row & 7) << 4))) = v;
        }
        // stage B: 256 cols x 128 bytes (32 KB)
        #pragma unroll
        for (int i = 0; i < 8; ++i) {
            const int p   = (i * 256 + tid) * 16;
            const int row = p >> 7;
            const int off = p & 127;
            uint4 v = *(const uint4*)((const char*)Bt + ((size_t)row * 512 + k0 * 2 + off));
            *(uint4*)((char*)sB + row * 128 + (off ^ ((row & 7) << 4))) = v;
        }
        __syncthreads();

        #pragma unroll
        for (int ks = 0; ks < 2; ++ks) {
            const int off1 = ks * 64 + 8 * g;       // bytes of k-halves
            const int off2 = off1 + 32;
            short8v bfrag[4];
            #pragma unroll
            for (int nb = 0; nb < 4; ++nb) {
                const int col = wv * 64 + nb * 16 + lrow;
                const int sw  = (col & 7) << 4;
                short4v lo = *(const short4v*)((const char*)sB + col * 128 + (off1 ^ sw));
                short4v hi = *(const short4v*)((const char*)sB + col * 128 + (off2 ^ sw));
                short8v b;
                b[0] = lo[0]; b[1] = lo[1]; b[2] = lo[2]; b[3] = lo[3];
                b[4] = hi[0]; b[5] = hi[1]; b[6] = hi[2]; b[7] = hi[3];
                bfrag[nb] = b;
            }
            #pragma unroll
            for (int mb = 0; mb < 8; ++mb) {
                const int row = mb * 16 + lrow;
                const int sw  = (row & 7) << 4;
                short4v lo = *(const short4v*)((const char*)sA + row * 128 + (off1 ^ sw));
                short4v hi = *(const short4v*)((const char*)sA + row * 128 + (off2 ^ sw));
                short8v a;
                a[0] = lo[0]; a[1] = lo[1]; a[2] = lo[2]; a[3] = lo[3];
                a[4] = hi[0]; a[5] = hi[1]; a[6] = hi[2]; a[7] = hi[3];
                #pragma unroll
                for (int nb = 0; nb < 4; ++nb)
                    acc[mb][nb] = __builtin_amdgcn_mfma_f32_16x16x32_bf16(a, bfrag[nb], acc[mb][nb], 0, 0, 0);
            }
        }
        __syncthreads();
    }

    // epilogue: C row = mb*16 + g*4 + r, col = wv*64 + nb*16 + lrow
    #pragma unroll
    for (int mb = 0; mb < 8; ++mb) {
        #pragma unroll
        for (int r = 0; r < 4; ++r) {
            const int row = m0 + mb * 16 + g * 4 + r;
            if (row >= M) continue;
            #pragma unroll
            for (int nb = 0; nb < 4; ++nb) {
                const int col = wv * 64 + nb * 16 + lrow;
                float v = acc[mb][nb][r] + bias[col];
                if constexpr (WITH_BN)
                    v = (v - mean[col]) * (gamma[col] * rsqrtf(var[col] + BN_EPS)) + beta[col];
                v = fmaxf(v, 0.f);
                if constexpr (OUT_F32)
                    ((float*)Cout)[(size_t)row * HID + col] = v;
                else
                    ((unsigned short*)Cout)[(size_t)row * HID + col] = f2bf(v);
            }
        }
    }
}

// ---------------- weight convert + transpose: Wt[n][k] = bf16(W[k][n]) ------
__global__ __launch_bounds__(256)
void convw_kernel(const float* __restrict__ W, unsigned short* __restrict__ Wt)
{
    // 8 matrices of 256x256
    size_t i = (size_t)blockIdx.x * 256 + threadIdx.x;   // over 8*65536
    const int mat = (int)(i >> 16);
    const int idx = (int)(i & 65535);
    const int n = idx >> 8, k = idx & 255;
    Wt[i] = f2bf(W[(size_t)mat * 65536 + (size_t)k * 256 + n]);
}

// ---------------- CSR build --------------------------------------------------
__global__ __launch_bounds__(256)
void deg_count_kernel(const int* __restrict__ dst, int* __restrict__ deg, int E)
{
    int e = blockIdx.x * 256 + threadIdx.x;
    if (e < E) atomicAdd(&deg[dst[e]], 1);
}

__global__ __launch_bounds__(256)
void scan1_kernel(const int* __restrict__ deg, int* __restrict__ rowptr,
                  int* __restrict__ bsum, int n)
{
    __shared__ int s[256];
    const int tid = threadIdx.x;
    const int i = blockIdx.x * 256 + tid;
    const int v = (i < n) ? deg[i] : 0;
    s[tid] = v;
    __syncthreads();
    #pragma unroll
    for (int d = 1; d < 256; d <<= 1) {
        int t = (tid >= d) ? s[tid - d] : 0;
        __syncthreads();
        s[tid] += t;
        __syncthreads();
    }
    if (i < n) rowptr[i] = s[tid] - v;       // exclusive
    if (tid == 255) bsum[blockIdx.x] = s[255];
}

__global__ void scan2_kernel(int* bsum, int nb, int* rowptr, int n)
{
    if (threadIdx.x == 0 && blockIdx.x == 0) {
        int run = 0;
        for (int j = 0; j < nb; ++j) { int t = bsum[j]; bsum[j] = run; run += t; }
        rowptr[n] = run;
    }
}

__global__ __launch_bounds__(256)
void scan3_kernel(int* __restrict__ rowptr, const int* __restrict__ bsum, int n)
{
    int i = blockIdx.x * 256 + threadIdx.x;
    if (i < n) rowptr[i] += bsum[i >> 8];
}

__global__ __launch_bounds__(256)
void scatter_kernel(const int* __restrict__ src, const int* __restrict__ dst,
                    const int* __restrict__ rowptr, int* __restrict__ fill,
                    int* __restrict__ esrc, int* __restrict__ eidx, int E)
{
    int e = blockIdx.x * 256 + threadIdx.x;
    if (e >= E) return;
    const int d = dst[e];
    const int pos = rowptr[d] + atomicAdd(&fill[d], 1);
    esrc[pos] = src[e];
    eidx[pos] = e;
}

// ---------------- fused CSR aggregation + z, write bf16 ---------------------
// z[n,t] = (1+eps)*h[n,t] + sum_{e into n} relu(h[src_e,t] + ea[e]·W[:,t] + b[t])
__global__ __launch_bounds__(256)
void agg_kernel(const float* __restrict__ h, const float* __restrict__ ea,
                const int* __restrict__ rowptr, const int* __restrict__ esrc,
                const int* __restrict__ eidx,
                const float* __restrict__ W, const float* __restrict__ b,
                const float* __restrict__ eps, int l,
                unsigned short* __restrict__ z)
{
    __shared__ float Ws[EDGE_IN][HID];
    __shared__ float bs[HID];
    const int t = threadIdx.x;
    #pragma unroll
    for (int k = 0; k < EDGE_IN; ++k) Ws[k][t] = W[k * HID + t];
    bs[t] = b[t];
    __syncthreads();

    const float e1 = 1.0f + eps[l];
    for (int n = blockIdx.x; n < N_NODES; n += gridDim.x) {
        const int beg = rowptr[n], end = rowptr[n + 1];
        float acc = e1 * h[(size_t)n * HID + t];
        for (int i = beg; i < end; ++i) {
            const int s = esrc[i];
            const int e = eidx[i];
            float ev = bs[t];
            #pragma unroll
            for (int k = 0; k < EDGE_IN; ++k) ev += ea[(size_t)e * EDGE_IN + k] * Ws[k][t];
            acc += fmaxf(h[(size_t)s * HID + t] + ev, 0.f);
        }
        z[(size_t)n * HID + t] = f2bf(acc);
    }
}

// ---------------- pool + head (unchanged) ------------------------------------
__global__ __launch_bounds__(256)
void pool_kernel(const float* __restrict__ h, const int* __restrict__ batch,
                 float* __restrict__ gsum, int* __restrict__ cnt, int n)
{
    __shared__ int bsh[256];
    const int t = threadIdx.x;
    const int n0 = blockIdx.x * 256;
    const int nn = min(256, n - n0);
    if (t < nn) bsh[t] = batch[n0 + t];
    __syncthreads();

    int gcur = bsh[0];
    float acc = 0.f;
    int c = 0;
    for (int i = 0; i < nn; ++i) {
        const int g = bsh[i];
        if (g != gcur) {
            atomicAdd(&gsum[gcur * HID + t], acc);
            if (t == 0) atomicAdd(&cnt[gcur], c);
            acc = 0.f; c = 0; gcur = g;
        }
        acc += h[(size_t)(n0 + i) * HID + t];
        c++;
    }
    atomicAdd(&gsum[gcur * HID + t], acc);
    if (t == 0) atomicAdd(&cnt[gcur], c);
}

__global__ __launch_bounds__(128)
void head_kernel(const float* __restrict__ gsum, const int* __restrict__ cnt,
                 const float* __restrict__ W1, const float* __restrict__ b1,
                 const float* __restrict__ W2, const float* __restrict__ b2,
                 float* __restrict__ out)
{
    const int gi = blockIdx.x;
    const int j = threadIdx.x;
    __shared__ float gs[HID];
    __shared__ float red[128];

    const float c = fmaxf((float)cnt[gi], 1.0f);
    gs[j]       = gsum[gi * HID + j] / c;
    gs[j + 128] = gsum[gi * HID + 128 + j] / c;
    __syncthreads();

    float acc = b1[j];
    #pragma unroll 8
    for (int k = 0; k < HID; ++k) acc += gs[k] * W1[k * 128 + j];
    acc = fmaxf(acc, 0.f);
    red[j] = acc * W2[j];
    __syncthreads();
    for (int s = 64; s > 0; s >>= 1) {
        if (j < s) red[j] += red[j + s];
        __syncthreads();
    }
    if (j == 0) out[gi] = red[0] + b2[0];
}

extern "C" void kernel_launch(void* const* d_in, const int* in_sizes, int n_in,
                              void* d_out, int out_size, void* d_ws, size_t ws_size,
                              hipStream_t stream)
{
    const float* x         = (const float*)d_in[0];
    const int*   ei        = (const int*)d_in[1];
    const float* edge_attr = (const float*)d_in[2];
    const int*   batch     = (const int*)d_in[3];
    const float* xproj_W   = (const float*)d_in[4];
    const float* xproj_b   = (const float*)d_in[5];
    const float* xp_gamma  = (const float*)d_in[6];
    const float* xp_beta   = (const float*)d_in[7];
    const float* xp_mean   = (const float*)d_in[8];
    const float* xp_var    = (const float*)d_in[9];
    const float* edge_W    = (const float*)d_in[10];
    const float* edge_b    = (const float*)d_in[11];
    const float* mlp_W1    = (const float*)d_in[12];
    const float* mlp_b1    = (const float*)d_in[13];
    const float* mlp_W2    = (const float*)d_in[14];
    const float* mlp_b2    = (const float*)d_in[15];
    const float* eps       = (const float*)d_in[16];
    const float* bn_gamma  = (const float*)d_in[17];
    const float* bn_beta   = (const float*)d_in[18];
    const float* bn_mean   = (const float*)d_in[19];
    const float* bn_var    = (const float*)d_in[20];
    const float* head_W1   = (const float*)d_in[21];
    const float* head_b1   = (const float*)d_in[22];
    const float* head_W2   = (const float*)d_in[23];
    const float* head_b2   = (const float*)d_in[24];
    float* out = (float*)d_out;

    const int* srcI = ei;
    const int* dstI = ei + N_EDGES;

    // ---- workspace layout (~161 MB) ----
    float*          h      = (float*)d_ws;                     // 25.6M floats
    unsigned short* zy     = (unsigned short*)(h + (size_t)N_NODES * HID);   // 25.6M bf16
    unsigned short* Wt1    = zy + (size_t)N_NODES * HID;       // 8*65536
    unsigned short* Wt2    = Wt1 + (size_t)NLAYERS * 65536;    // 8*65536
    int*            rowptr = (int*)(Wt2 + (size_t)NLAYERS * 65536); // 100032
    int*            deg    = rowptr + 100032;                  // 100032
    int*            fill   = deg + 100032;                     // 100032
    int*            bsum   = fill + 100032;                    // 512
    int*            esrc   = bsum + 512;                       // 500000
    int*            eidx   = esrc + N_EDGES;                   // 500000
    float*          gsum   = (float*)(eidx + N_EDGES);         // 16384
    int*            cnt    = (int*)(gsum + NGRAPH * HID);      // 64

    // ---- one-time prep: weight convert + CSR build ----
    convw_kernel<<<2048, 256, 0, stream>>>(mlp_W1, Wt1);
    convw_kernel<<<2048, 256, 0, stream>>>(mlp_W2, Wt2);

    hipMemsetAsync(deg, 0, 2 * 100032 * sizeof(int), stream);  // deg + fill
    deg_count_kernel<<<(N_EDGES + 255) / 256, 256, 0, stream>>>(dstI, deg, N_EDGES);
    scan1_kernel<<<391, 256, 0, stream>>>(deg, rowptr, bsum, N_NODES);
    scan2_kernel<<<1, 64, 0, stream>>>(bsum, 391, rowptr, N_NODES);
    scan3_kernel<<<391, 256, 0, stream>>>(rowptr, bsum, N_NODES);
    scatter_kernel<<<(N_EDGES + 255) / 256, 256, 0, stream>>>(srcI, dstI, rowptr, fill, esrc, eidx, N_EDGES);

    // ---- x_proj: Linear + BN + ReLU -> h (f32) ----
    dim3 xg((N_NODES + 63) / 64, HID / 64);
    gemm_f32_kernel<<<xg, 256, 0, stream>>>(
        x, NODE_IN, NODE_IN, xproj_W, xproj_b,
        xp_gamma, xp_beta, xp_mean, xp_var, h, N_NODES);

    const int gemm_grid = (N_NODES + 127) / 128;
    for (int l = 0; l < NLAYERS; ++l) {
        agg_kernel<<<2048, 256, 0, stream>>>(
            h, edge_attr, rowptr, esrc, eidx,
            edge_W + (size_t)l * EDGE_IN * HID, edge_b + (size_t)l * HID,
            eps, l, zy);
        mfma_gemm<false, false><<<gemm_grid, 256, 0, stream>>>(
            zy, Wt1 + (size_t)l * 65536, mlp_b1 + (size_t)l * HID,
            nullptr, nullptr, nullptr, nullptr, zy, N_NODES);
        mfma_gemm<true, true><<<gemm_grid, 256, 0, stream>>>(
            zy, Wt2 + (size_t)l * 65536, mlp_b2 + (size_t)l * HID,
            bn_gamma + (size_t)l * HID, bn_beta + (size_t)l * HID,
            bn_mean + (size_t)l * HID, bn_var + (size_t)l * HID, h, N_NODES);
    }

    hipMemsetAsync(gsum, 0, (NGRAPH * HID + NGRAPH) * sizeof(float), stream);
    pool_kernel<<<(N_NODES + 255) / 256, 256, 0, stream>>>(h, batch, gsum, cnt, N_NODES);
    head_kernel<<<NGRAPH, 128, 0, stream>>>(gsum, cnt, head_W1, head_b1, head_W2, head_b2, out);
}